// Round 1
// 206.132 us; speedup vs baseline: 1.1059x; 1.1059x over previous
//
#include <hip/hip_runtime.h>
#include <hip/hip_bf16.h>
#include <stdint.h>
#include <stddef.h>

// GlobalLSTMCell — f32 in/out, bf16 MFMA compute.
//   ifo = sigmoid(x@W_ifo_x + b_ifo_x + h@W_ifo_h + b_ifo_h); i,f,o = split
//   a   = tanh(x@W_b_x + b_b_x + h@W_b_h + b_b_h)
//   c   = i*a + f*c_prev ; h = o*tanh(c) ; out = [h ; c] f32.
// R4: GEMM rebuilt as 256x256/BK64 8-wave double-buffered counted-vmcnt
//     structure (T2 swizzle + T3/T4 counted vmcnt(8) + T5 setprio).
//     pack_all: wt (transpose) blocks dispatch FIRST so the cheap xh blocks
//     hide the wt tail; otherwise unchanged (diagnose with counters next).

#define BATCH 4096
#define FEAT  1024
#define HID   1024
#define NCAT  4096
#define KCAT  2048

typedef __attribute__((ext_vector_type(8))) __bf16 bf16x8;
typedef __attribute__((ext_vector_type(4))) float  floatx4;

__device__ __forceinline__ unsigned short f2bf(float f) {
    __hip_bfloat16 b = __float2bfloat16(f);
    return *reinterpret_cast<unsigned short*>(&b);
}
__device__ __forceinline__ void gl2lds16(const unsigned short* g, unsigned short* l) {
    __builtin_amdgcn_global_load_lds(
        (const __attribute__((address_space(1))) void*)g,
        (__attribute__((address_space(3))) void*)l, 16, 0, 0);
}

// ---------------- fused pack: Wt first, then Xcat ----------------
// blocks [0,2048):   weight transpose tile (heavy -> dispatch first).
// blocks [2048,6144): Xcat[m][k] = bf16([x | h_prev][m][k]) (cheap tail filler).
//   Virtual W_cat[k][q]: k<1024 x-weights else h-weights; q<3072 -> W_ifo (g=q>>10,
//   j=q&1023) else W_b (g=3, j=q-3072). Dest Wt[np][k], np=(j>>4)*64+g*16+(j&15).
#define TP_PAD 72   // u16 row stride; 144 B = 9*16 -> uint4-aligned rows, odd word shift
__global__ __launch_bounds__(256)
void pack_all(const float* __restrict__ x, const float* __restrict__ h,
              const float* __restrict__ Wix, const float* __restrict__ Wih,
              const float* __restrict__ Wbx, const float* __restrict__ Wbh,
              unsigned short* __restrict__ Xcat, unsigned short* __restrict__ Wt) {
    __shared__ unsigned short tile[64 * TP_PAD];
    const int t = threadIdx.x;
    const int b = blockIdx.x;
    if (b >= 2048) {
        // ---- xh part: one row m, 2048 elems, 8 per thread ----
        const int m = b - 2048;
        const float* src = (t < 128) ? (x + (size_t)m * FEAT + t * 8)
                                     : (h + (size_t)m * HID + (t - 128) * 8);
        float4 v0 = *(const float4*)src;
        float4 v1 = *(const float4*)(src + 4);
        union { unsigned short s16[8]; uint4 v; } pk;
        pk.s16[0] = f2bf(v0.x); pk.s16[1] = f2bf(v0.y);
        pk.s16[2] = f2bf(v0.z); pk.s16[3] = f2bf(v0.w);
        pk.s16[4] = f2bf(v1.x); pk.s16[5] = f2bf(v1.y);
        pk.s16[6] = f2bf(v1.z); pk.s16[7] = f2bf(v1.w);
        *(uint4*)(Xcat + (size_t)m * KCAT + t * 8) = pk.v;
        return;
    }
    // ---- wt part: 64x64 tile transpose ----
    const int tid = b;
    const int k0  = (tid & 31) * 64;
    const int q0  = (tid >> 5) * 64;
    const float* src; int stride, cb;
    if (q0 < 3072) { src = (k0 < FEAT) ? Wix : Wih; stride = 3072; cb = q0; }
    else           { src = (k0 < FEAT) ? Wbx : Wbh; stride = 1024; cb = q0 - 3072; }
    const int krow = (k0 < FEAT) ? k0 : (k0 - FEAT);
    {   // load 64x64 (k x q) coalesced on q, cvt bf16, vector LDS stores
        int kl = t >> 2;
        int c0 = (t & 3) * 16;
        const float* s = src + (size_t)(krow + kl) * stride + cb + c0;
        union { unsigned short s16[16]; uint4 v[2]; } tmp;
#pragma unroll
        for (int u = 0; u < 16; u += 4) {
            float4 v = *(const float4*)(s + u);
            tmp.s16[u + 0] = f2bf(v.x); tmp.s16[u + 1] = f2bf(v.y);
            tmp.s16[u + 2] = f2bf(v.z); tmp.s16[u + 3] = f2bf(v.w);
        }
        *(uint4*)&tile[kl * TP_PAD + c0]     = tmp.v[0];
        *(uint4*)&tile[kl * TP_PAD + c0 + 8] = tmp.v[1];
    }
    __syncthreads();
    {   // transpose out: thread = (q-col nl, k-chunk seg)
        int nl = t >> 2, seg = t & 3;
        int q = q0 + nl;
        int g, j;
        if (q < 3072) { g = q >> 10; j = q & 1023; }
        else          { g = 3;       j = q - 3072; }
        int np = ((j >> 4) << 6) + (g << 4) + (j & 15);
        union { unsigned short s16[16]; uint4 v[2]; } pk;
#pragma unroll
        for (int u = 0; u < 16; ++u)
            pk.s16[u] = tile[(seg * 16 + u) * TP_PAD + nl];
        uint4* dst = (uint4*)(Wt + (size_t)np * KCAT + k0 + seg * 16);
        dst[0] = pk.v[0];
        dst[1] = pk.v[1];
    }
}

// ---------------- fused GEMM + LSTM epilogue (256x256, BK=64) ----------------
#define BM 256
#define BN 256
#define BK 64
#define KT (KCAT / BK)   // 32 K-tiles

// Stage one K-tile (A 32KB + B 32KB) via global_load_lds width=16.
// LDS dest is LINEAR (slot*16B); swizzle (chunk ^= row&7) is applied on the
// GLOBAL source so the read side can use the same XOR (both-sides rule, m231).
__device__ __forceinline__ void stage_kt(
    const unsigned short* __restrict__ Xcat, const unsigned short* __restrict__ Wt,
    unsigned short* __restrict__ Adst, unsigned short* __restrict__ Bdst,
    int m0, int n0, int kko, int t) {
#pragma unroll
    for (int u = 0; u < 4; ++u) {
        int slot = t + u * 512;                 // slot = row*8 + chunk
        int row  = slot >> 3;
        int sch  = ((slot & 7) ^ (row & 7)) * 8;
        gl2lds16(Xcat + (size_t)(m0 + row) * KCAT + kko + sch, Adst + slot * 8);
    }
#pragma unroll
    for (int u = 0; u < 4; ++u) {
        int slot = t + u * 512;
        int row  = slot >> 3;
        int sch  = ((slot & 7) ^ (row & 7)) * 8;
        gl2lds16(Wt + (size_t)(n0 + row) * KCAT + kko + sch, Bdst + slot * 8);
    }
}

__global__ __launch_bounds__(512, 2)
void lstm_fused(const unsigned short* __restrict__ Xcat,
                const unsigned short* __restrict__ Wt,
                const float* __restrict__ c_prev,
                const float* __restrict__ bix, const float* __restrict__ bih,
                const float* __restrict__ bbx, const float* __restrict__ bbh,
                float* __restrict__ out_h, float* __restrict__ out_c) {
    __shared__ unsigned short As[2][BM * BK];   // 2 x 32 KB
    __shared__ unsigned short Bs[2][BN * BK];   // 2 x 32 KB  (128 KiB total)
    const int t    = threadIdx.x;
    const int lane = t & 63;
    const int wid  = t >> 6;                    // 0..7
    const int wm   = (wid >> 2) * 128;          // M-half of block tile
    const int wn   = (wid & 3) * 64;            // N-quarter (one gate-group)
    const int m0   = blockIdx.y * BM;
    const int n0   = blockIdx.x * BN;
    const int lm   = lane & 15;
    const int lk   = lane >> 4;                 // k-chunk within frag
    const int lx   = lane & 7;                  // row&7 of frag rows -> XOR key

    floatx4 acc[8][4];
#pragma unroll
    for (int i = 0; i < 8; ++i)
#pragma unroll
        for (int g = 0; g < 4; ++g) acc[i][g] = (floatx4){0.f, 0.f, 0.f, 0.f};

    // ---- prologue: stage K-tiles 0 and 1 ----
    stage_kt(Xcat, Wt, &As[0][0], &Bs[0][0], m0, n0, 0,  t);
    stage_kt(Xcat, Wt, &As[1][0], &Bs[1][0], m0, n0, BK, t);
    asm volatile("s_waitcnt vmcnt(8)" ::: "memory");   // K-tile 0 landed
    __builtin_amdgcn_s_barrier();
    asm volatile("" ::: "memory");

    for (int kt = 0; kt < KT; ++kt) {
        const unsigned short* Ab = &As[kt & 1][0];
        const unsigned short* Bb = &Bs[kt & 1][0];

        // B fragments for the whole K-tile (4 gates x 2 k-slices) — reused
        // across both M-halves so LDS reads stay at 24 b128 / K-tile / wave.
        bf16x8 bb[4][2];
#pragma unroll
        for (int g = 0; g < 4; ++g) {
            int c = wn + g * 16 + lm;
#pragma unroll
            for (int ks = 0; ks < 2; ++ks)
                bb[g][ks] = *(const bf16x8*)&Bb[c * BK + (((ks * 4 + lk) ^ lx) * 8)];
        }
#pragma unroll
        for (int mh = 0; mh < 2; ++mh) {
            bf16x8 aa[4][2];
#pragma unroll
            for (int i = 0; i < 4; ++i) {
                int r = wm + mh * 64 + i * 16 + lm;
#pragma unroll
                for (int ks = 0; ks < 2; ++ks)
                    aa[i][ks] = *(const bf16x8*)&Ab[r * BK + (((ks * 4 + lk) ^ lx) * 8)];
            }
            __builtin_amdgcn_s_setprio(1);
#pragma unroll
            for (int i = 0; i < 4; ++i)
#pragma unroll
                for (int g = 0; g < 4; ++g)
#pragma unroll
                    for (int ks = 0; ks < 2; ++ks)
                        acc[mh * 4 + i][g] = __builtin_amdgcn_mfma_f32_16x16x32_bf16(
                            aa[i][ks], bb[g][ks], acc[mh * 4 + i][g], 0, 0, 0);
            __builtin_amdgcn_s_setprio(0);
        }

        // ---- K-tile boundary: refill the buffer just consumed ----
        if (kt + 1 < KT) {
            asm volatile("" ::: "memory");
            __builtin_amdgcn_s_barrier();          // all waves done reading cur
            if (kt + 2 < KT) {
                stage_kt(Xcat, Wt, &As[kt & 1][0], &Bs[kt & 1][0],
                         m0, n0, (kt + 2) * BK, t);
                // keep kt+2's 8 loads in flight; wait only for kt+1's
                asm volatile("s_waitcnt vmcnt(8)" ::: "memory");
            } else {
                asm volatile("s_waitcnt vmcnt(0)" ::: "memory");
            }
            __builtin_amdgcn_s_barrier();          // all waves' kt+1 loads landed
            asm volatile("" ::: "memory");
        }
    }

    // ---- LSTM epilogue ----
    // acc[idx][g][r]: m = m0 + wm + idx*16 + (lane>>4)*4 + r,
    //                 gate g at j = ((n0+wn)>>6)*16 + lm.
    const int j  = (((n0 + wn) >> 6) << 4) + lm;
    const float bi = bix[j]           + bih[j];
    const float bf = bix[HID + j]     + bih[HID + j];
    const float bo = bix[2 * HID + j] + bih[2 * HID + j];
    const float ba = bbx[j]           + bbh[j];
#pragma unroll
    for (int i = 0; i < 8; ++i) {
#pragma unroll
        for (int r = 0; r < 4; ++r) {
            int m = m0 + wm + i * 16 + (lk * 4) + r;
            float pi = acc[i][0][r] + bi;
            float pf = acc[i][1][r] + bf;
            float po = acc[i][2][r] + bo;
            float pa = acc[i][3][r] + ba;
            float ig = 1.f / (1.f + __expf(-pi));
            float fg = 1.f / (1.f + __expf(-pf));
            float og = 1.f / (1.f + __expf(-po));
            float av = 2.f / (1.f + __expf(-2.f * pa)) - 1.f;
            float cp = c_prev[(size_t)m * HID + j];
            float cv = ig * av + fg * cp;
            float hv = og * (2.f / (1.f + __expf(-2.f * cv)) - 1.f);
            out_h[(size_t)m * HID + j] = hv;
            out_c[(size_t)m * HID + j] = cv;
        }
    }
}

// ---------------- naive fallback (ws too small) ----------------
__global__ void naive_lstm(const float* __restrict__ x, const float* __restrict__ h,
                           const float* __restrict__ cvp,
                           const float* __restrict__ Wix, const float* __restrict__ bix,
                           const float* __restrict__ Wih, const float* __restrict__ bih,
                           const float* __restrict__ Wbx, const float* __restrict__ bbx,
                           const float* __restrict__ Wbh, const float* __restrict__ bbh,
                           float* __restrict__ out_h, float* __restrict__ out_c) {
    const int j = blockIdx.x * 256 + threadIdx.x;
    const int m = blockIdx.y;
    float ai = 0.f, af = 0.f, ao = 0.f, aa = 0.f;
    for (int k = 0; k < FEAT; ++k) {
        float xk = x[(size_t)m * FEAT + k];
        ai += xk * Wix[(size_t)k * 3072 + j];
        af += xk * Wix[(size_t)k * 3072 + HID + j];
        ao += xk * Wix[(size_t)k * 3072 + 2 * HID + j];
        aa += xk * Wbx[(size_t)k * HID + j];
    }
    for (int k = 0; k < HID; ++k) {
        float hk = h[(size_t)m * HID + k];
        ai += hk * Wih[(size_t)k * 3072 + j];
        af += hk * Wih[(size_t)k * 3072 + HID + j];
        ao += hk * Wih[(size_t)k * 3072 + 2 * HID + j];
        aa += hk * Wbh[(size_t)k * HID + j];
    }
    ai += bix[j] + bih[j];
    af += bix[HID + j] + bih[HID + j];
    ao += bix[2 * HID + j] + bih[2 * HID + j];
    aa += bbx[j] + bbh[j];
    float ig = 1.f / (1.f + __expf(-ai));
    float fg = 1.f / (1.f + __expf(-af));
    float og = 1.f / (1.f + __expf(-ao));
    float av = 2.f / (1.f + __expf(-2.f * aa)) - 1.f;
    float cp = cvp[(size_t)m * HID + j];
    float cc = ig * av + fg * cp;
    float hh = og * (2.f / (1.f + __expf(-2.f * cc)) - 1.f);
    out_h[(size_t)m * HID + j] = hh;
    out_c[(size_t)m * HID + j] = cc;
}

extern "C" void kernel_launch(void* const* d_in, const int* in_sizes, int n_in,
                              void* d_out, int out_size, void* d_ws, size_t ws_size,
                              hipStream_t stream) {
    const float* x   = (const float*)d_in[0];
    const float* h   = (const float*)d_in[1];
    const float* c   = (const float*)d_in[2];
    const float* Wix = (const float*)d_in[3];
    const float* bix = (const float*)d_in[4];
    const float* Wih = (const float*)d_in[5];
    const float* bih = (const float*)d_in[6];
    const float* Wbx = (const float*)d_in[7];
    const float* bbx = (const float*)d_in[8];
    const float* Wbh = (const float*)d_in[9];
    const float* bbh = (const float*)d_in[10];

    float* out_h = (float*)d_out;
    float* out_c = out_h + (size_t)BATCH * HID;

    const size_t WT_BYTES = (size_t)NCAT * KCAT * 2;    // 16 MiB
    const size_t XC_BYTES = (size_t)BATCH * KCAT * 2;   // 16 MiB
    if (ws_size >= WT_BYTES + XC_BYTES) {
        unsigned short* Wt   = (unsigned short*)d_ws;
        unsigned short* Xcat = (unsigned short*)((char*)d_ws + WT_BYTES);
        pack_all<<<BATCH + 2048, 256, 0, stream>>>(x, h, Wix, Wih, Wbx, Wbh, Xcat, Wt);
        lstm_fused<<<dim3(NCAT / BN, BATCH / BM), 512, 0, stream>>>(
            Xcat, Wt, c, bix, bih, bbx, bbh, out_h, out_c);
    } else {
        naive_lstm<<<dim3(HID / 256, BATCH), 256, 0, stream>>>(
            x, h, c, Wix, bix, Wih, bih, Wbx, bbx, Wbh, bbh, out_h, out_c);
    }
}

// Round 2
// 204.773 us; speedup vs baseline: 1.1132x; 1.0066x over previous
//
#include <hip/hip_runtime.h>
#include <hip/hip_bf16.h>
#include <stdint.h>
#include <stddef.h>

// GlobalLSTMCell — f32 in/out, bf16 MFMA compute.
//   ifo = sigmoid(x@W_ifo_x + b_ifo_x + h@W_ifo_h + b_ifo_h); i,f,o = split
//   a   = tanh(x@W_b_x + b_b_x + h@W_b_h + b_b_h)
//   c   = i*a + f*c_prev ; h = o*tanh(c) ; out = [h ; c] f32.
// R5: lstm_fused was FEED-bound (staging 64KB/CU/K-tile at 5.9 TB/s aggregate
//     == measured K-tile time; no XCD locality -> L2 miss storm). Add T1
//     bijective XCD swizzle: each XCD owns a 4(M)x8(N) tile chunk -> 384 KB
//     L2 working set per K-tile, feed served from L2 (34.5 TB/s aggregate).
//     pack_all: xh rows batched 4/block (fewer launches); wt path unchanged —
//     waiting for its counters to surface before touching it.

#define BATCH 4096
#define FEAT  1024
#define HID   1024
#define NCAT  4096
#define KCAT  2048

typedef __attribute__((ext_vector_type(8))) __bf16 bf16x8;
typedef __attribute__((ext_vector_type(4))) float  floatx4;

__device__ __forceinline__ unsigned short f2bf(float f) {
    __hip_bfloat16 b = __float2bfloat16(f);
    return *reinterpret_cast<unsigned short*>(&b);
}
__device__ __forceinline__ void gl2lds16(const unsigned short* g, unsigned short* l) {
    __builtin_amdgcn_global_load_lds(
        (const __attribute__((address_space(1))) void*)g,
        (__attribute__((address_space(3))) void*)l, 16, 0, 0);
}

// ---------------- fused pack: Wt first, then Xcat ----------------
// blocks [0,2048):      weight transpose tile (heavy -> dispatch first).
// blocks [2048,3072):   Xcat[m][k] = bf16([x | h_prev][m][k]), 4 rows/block.
//   Virtual W_cat[k][q]: k<1024 x-weights else h-weights; q<3072 -> W_ifo (g=q>>10,
//   j=q&1023) else W_b (g=3, j=q-3072). Dest Wt[np][k], np=(j>>4)*64+g*16+(j&15).
#define TP_PAD 72   // u16 row stride; 144 B = 9*16 -> uint4-aligned rows, odd word shift
__global__ __launch_bounds__(256)
void pack_all(const float* __restrict__ x, const float* __restrict__ h,
              const float* __restrict__ Wix, const float* __restrict__ Wih,
              const float* __restrict__ Wbx, const float* __restrict__ Wbh,
              unsigned short* __restrict__ Xcat, unsigned short* __restrict__ Wt) {
    __shared__ unsigned short tile[64 * TP_PAD];
    const int t = threadIdx.x;
    const int b = blockIdx.x;
    if (b >= 2048) {
        // ---- xh part: 4 rows per block, 8 elems per thread per row ----
        const int mbase = (b - 2048) * 4;
#pragma unroll
        for (int r = 0; r < 4; ++r) {
            const int m = mbase + r;
            const float* src = (t < 128) ? (x + (size_t)m * FEAT + t * 8)
                                         : (h + (size_t)m * HID + (t - 128) * 8);
            float4 v0 = *(const float4*)src;
            float4 v1 = *(const float4*)(src + 4);
            union { unsigned short s16[8]; uint4 v; } pk;
            pk.s16[0] = f2bf(v0.x); pk.s16[1] = f2bf(v0.y);
            pk.s16[2] = f2bf(v0.z); pk.s16[3] = f2bf(v0.w);
            pk.s16[4] = f2bf(v1.x); pk.s16[5] = f2bf(v1.y);
            pk.s16[6] = f2bf(v1.z); pk.s16[7] = f2bf(v1.w);
            *(uint4*)(Xcat + (size_t)m * KCAT + t * 8) = pk.v;
        }
        return;
    }
    // ---- wt part: 64x64 tile transpose ----
    const int tid = b;
    const int k0  = (tid & 31) * 64;
    const int q0  = (tid >> 5) * 64;
    const float* src; int stride, cb;
    if (q0 < 3072) { src = (k0 < FEAT) ? Wix : Wih; stride = 3072; cb = q0; }
    else           { src = (k0 < FEAT) ? Wbx : Wbh; stride = 1024; cb = q0 - 3072; }
    const int krow = (k0 < FEAT) ? k0 : (k0 - FEAT);
    {   // load 64x64 (k x q) coalesced on q, cvt bf16, vector LDS stores
        int kl = t >> 2;
        int c0 = (t & 3) * 16;
        const float* s = src + (size_t)(krow + kl) * stride + cb + c0;
        union { unsigned short s16[16]; uint4 v[2]; } tmp;
#pragma unroll
        for (int u = 0; u < 16; u += 4) {
            float4 v = *(const float4*)(s + u);
            tmp.s16[u + 0] = f2bf(v.x); tmp.s16[u + 1] = f2bf(v.y);
            tmp.s16[u + 2] = f2bf(v.z); tmp.s16[u + 3] = f2bf(v.w);
        }
        *(uint4*)&tile[kl * TP_PAD + c0]     = tmp.v[0];
        *(uint4*)&tile[kl * TP_PAD + c0 + 8] = tmp.v[1];
    }
    __syncthreads();
    {   // transpose out: thread = (q-col nl, k-chunk seg)
        int nl = t >> 2, seg = t & 3;
        int q = q0 + nl;
        int g, j;
        if (q < 3072) { g = q >> 10; j = q & 1023; }
        else          { g = 3;       j = q - 3072; }
        int np = ((j >> 4) << 6) + (g << 4) + (j & 15);
        union { unsigned short s16[16]; uint4 v[2]; } pk;
#pragma unroll
        for (int u = 0; u < 16; ++u)
            pk.s16[u] = tile[(seg * 16 + u) * TP_PAD + nl];
        uint4* dst = (uint4*)(Wt + (size_t)np * KCAT + k0 + seg * 16);
        dst[0] = pk.v[0];
        dst[1] = pk.v[1];
    }
}

// ---------------- fused GEMM + LSTM epilogue (256x256, BK=64) ----------------
#define BM 256
#define BN 256
#define BK 64
#define KT (KCAT / BK)   // 32 K-tiles

// Stage one K-tile (A 32KB + B 32KB) via global_load_lds width=16.
// LDS dest is LINEAR (slot*16B); swizzle (chunk ^= row&7) is applied on the
// GLOBAL source so the read side can use the same XOR (both-sides rule, m231).
__device__ __forceinline__ void stage_kt(
    const unsigned short* __restrict__ Xcat, const unsigned short* __restrict__ Wt,
    unsigned short* __restrict__ Adst, unsigned short* __restrict__ Bdst,
    int m0, int n0, int kko, int t) {
#pragma unroll
    for (int u = 0; u < 4; ++u) {
        int slot = t + u * 512;                 // slot = row*8 + chunk
        int row  = slot >> 3;
        int sch  = ((slot & 7) ^ (row & 7)) * 8;
        gl2lds16(Xcat + (size_t)(m0 + row) * KCAT + kko + sch, Adst + slot * 8);
    }
#pragma unroll
    for (int u = 0; u < 4; ++u) {
        int slot = t + u * 512;
        int row  = slot >> 3;
        int sch  = ((slot & 7) ^ (row & 7)) * 8;
        gl2lds16(Wt + (size_t)(n0 + row) * KCAT + kko + sch, Bdst + slot * 8);
    }
}

__global__ __launch_bounds__(512, 2)
void lstm_fused(const unsigned short* __restrict__ Xcat,
                const unsigned short* __restrict__ Wt,
                const float* __restrict__ c_prev,
                const float* __restrict__ bix, const float* __restrict__ bih,
                const float* __restrict__ bbx, const float* __restrict__ bbh,
                float* __restrict__ out_h, float* __restrict__ out_c) {
    __shared__ unsigned short As[2][BM * BK];   // 2 x 32 KB
    __shared__ unsigned short Bs[2][BN * BK];   // 2 x 32 KB  (128 KiB total)
    const int t    = threadIdx.x;
    const int lane = t & 63;
    const int wid  = t >> 6;                    // 0..7
    const int wm   = (wid >> 2) * 128;          // M-half of block tile
    const int wn   = (wid & 3) * 64;            // N-quarter (one gate-group)

    // T1: bijective XCD-chunk swizzle. Dispatch-linear id round-robins across
    // the 8 XCDs (id&7); give each XCD a contiguous 4(M)x8(N) tile chunk so
    // its 32 co-resident blocks share 4 A-panels + 8 B-panels (384 KB/K-tile
    // in its private L2 instead of a scattered multi-MiB working set).
    const int lid = blockIdx.y * gridDim.x + blockIdx.x;   // 0..255
    const int xcd = lid & 7;
    const int loc = lid >> 3;                              // 0..31
    const int my  = (xcd >> 1) * 4 + (loc >> 3);           // 0..15
    const int nx  = (xcd & 1) * 8 + (loc & 7);             // 0..15
    const int m0  = my * BM;
    const int n0  = nx * BN;

    const int lm   = lane & 15;
    const int lk   = lane >> 4;                 // k-chunk within frag
    const int lx   = lane & 7;                  // row&7 of frag rows -> XOR key

    floatx4 acc[8][4];
#pragma unroll
    for (int i = 0; i < 8; ++i)
#pragma unroll
        for (int g = 0; g < 4; ++g) acc[i][g] = (floatx4){0.f, 0.f, 0.f, 0.f};

    // ---- prologue: stage K-tiles 0 and 1 ----
    stage_kt(Xcat, Wt, &As[0][0], &Bs[0][0], m0, n0, 0,  t);
    stage_kt(Xcat, Wt, &As[1][0], &Bs[1][0], m0, n0, BK, t);
    asm volatile("s_waitcnt vmcnt(8)" ::: "memory");   // K-tile 0 landed
    __builtin_amdgcn_s_barrier();
    asm volatile("" ::: "memory");

    for (int kt = 0; kt < KT; ++kt) {
        const unsigned short* Ab = &As[kt & 1][0];
        const unsigned short* Bb = &Bs[kt & 1][0];

        // B fragments for the whole K-tile (4 gates x 2 k-slices) — reused
        // across both M-halves so LDS reads stay at 24 b128 / K-tile / wave.
        bf16x8 bb[4][2];
#pragma unroll
        for (int g = 0; g < 4; ++g) {
            int c = wn + g * 16 + lm;
#pragma unroll
            for (int ks = 0; ks < 2; ++ks)
                bb[g][ks] = *(const bf16x8*)&Bb[c * BK + (((ks * 4 + lk) ^ lx) * 8)];
        }
#pragma unroll
        for (int mh = 0; mh < 2; ++mh) {
            bf16x8 aa[4][2];
#pragma unroll
            for (int i = 0; i < 4; ++i) {
                int r = wm + mh * 64 + i * 16 + lm;
#pragma unroll
                for (int ks = 0; ks < 2; ++ks)
                    aa[i][ks] = *(const bf16x8*)&Ab[r * BK + (((ks * 4 + lk) ^ lx) * 8)];
            }
            __builtin_amdgcn_s_setprio(1);
#pragma unroll
            for (int i = 0; i < 4; ++i)
#pragma unroll
                for (int g = 0; g < 4; ++g)
#pragma unroll
                    for (int ks = 0; ks < 2; ++ks)
                        acc[mh * 4 + i][g] = __builtin_amdgcn_mfma_f32_16x16x32_bf16(
                            aa[i][ks], bb[g][ks], acc[mh * 4 + i][g], 0, 0, 0);
            __builtin_amdgcn_s_setprio(0);
        }

        // ---- K-tile boundary: refill the buffer just consumed ----
        if (kt + 1 < KT) {
            asm volatile("" ::: "memory");
            __builtin_amdgcn_s_barrier();          // all waves done reading cur
            if (kt + 2 < KT) {
                stage_kt(Xcat, Wt, &As[kt & 1][0], &Bs[kt & 1][0],
                         m0, n0, (kt + 2) * BK, t);
                // keep kt+2's 8 loads in flight; wait only for kt+1's
                asm volatile("s_waitcnt vmcnt(8)" ::: "memory");
            } else {
                asm volatile("s_waitcnt vmcnt(0)" ::: "memory");
            }
            __builtin_amdgcn_s_barrier();          // all waves' kt+1 loads landed
            asm volatile("" ::: "memory");
        }
    }

    // ---- LSTM epilogue ----
    // acc[idx][g][r]: m = m0 + wm + idx*16 + (lane>>4)*4 + r,
    //                 gate g at j = ((n0+wn)>>6)*16 + lm.
    const int j  = (((n0 + wn) >> 6) << 4) + lm;
    const float bi = bix[j]           + bih[j];
    const float bf = bix[HID + j]     + bih[HID + j];
    const float bo = bix[2 * HID + j] + bih[2 * HID + j];
    const float ba = bbx[j]           + bbh[j];
#pragma unroll
    for (int i = 0; i < 8; ++i) {
#pragma unroll
        for (int r = 0; r < 4; ++r) {
            int m = m0 + wm + i * 16 + (lk * 4) + r;
            float pi = acc[i][0][r] + bi;
            float pf = acc[i][1][r] + bf;
            float po = acc[i][2][r] + bo;
            float pa = acc[i][3][r] + ba;
            float ig = 1.f / (1.f + __expf(-pi));
            float fg = 1.f / (1.f + __expf(-pf));
            float og = 1.f / (1.f + __expf(-po));
            float av = 2.f / (1.f + __expf(-2.f * pa)) - 1.f;
            float cp = c_prev[(size_t)m * HID + j];
            float cv = ig * av + fg * cp;
            float hv = og * (2.f / (1.f + __expf(-2.f * cv)) - 1.f);
            out_h[(size_t)m * HID + j] = hv;
            out_c[(size_t)m * HID + j] = cv;
        }
    }
}

// ---------------- naive fallback (ws too small) ----------------
__global__ void naive_lstm(const float* __restrict__ x, const float* __restrict__ h,
                           const float* __restrict__ cvp,
                           const float* __restrict__ Wix, const float* __restrict__ bix,
                           const float* __restrict__ Wih, const float* __restrict__ bih,
                           const float* __restrict__ Wbx, const float* __restrict__ bbx,
                           const float* __restrict__ Wbh, const float* __restrict__ bbh,
                           float* __restrict__ out_h, float* __restrict__ out_c) {
    const int j = blockIdx.x * 256 + threadIdx.x;
    const int m = blockIdx.y;
    float ai = 0.f, af = 0.f, ao = 0.f, aa = 0.f;
    for (int k = 0; k < FEAT; ++k) {
        float xk = x[(size_t)m * FEAT + k];
        ai += xk * Wix[(size_t)k * 3072 + j];
        af += xk * Wix[(size_t)k * 3072 + HID + j];
        ao += xk * Wix[(size_t)k * 3072 + 2 * HID + j];
        aa += xk * Wbx[(size_t)k * HID + j];
    }
    for (int k = 0; k < HID; ++k) {
        float hk = h[(size_t)m * HID + k];
        ai += hk * Wih[(size_t)k * 3072 + j];
        af += hk * Wih[(size_t)k * 3072 + HID + j];
        ao += hk * Wih[(size_t)k * 3072 + 2 * HID + j];
        aa += hk * Wbh[(size_t)k * HID + j];
    }
    ai += bix[j] + bih[j];
    af += bix[HID + j] + bih[HID + j];
    ao += bix[2 * HID + j] + bih[2 * HID + j];
    aa += bbx[j] + bbh[j];
    float ig = 1.f / (1.f + __expf(-ai));
    float fg = 1.f / (1.f + __expf(-af));
    float og = 1.f / (1.f + __expf(-ao));
    float av = 2.f / (1.f + __expf(-2.f * aa)) - 1.f;
    float cp = cvp[(size_t)m * HID + j];
    float cc = ig * av + fg * cp;
    float hh = og * (2.f / (1.f + __expf(-2.f * cc)) - 1.f);
    out_h[(size_t)m * HID + j] = hh;
    out_c[(size_t)m * HID + j] = cc;
}

extern "C" void kernel_launch(void* const* d_in, const int* in_sizes, int n_in,
                              void* d_out, int out_size, void* d_ws, size_t ws_size,
                              hipStream_t stream) {
    const float* x   = (const float*)d_in[0];
    const float* h   = (const float*)d_in[1];
    const float* c   = (const float*)d_in[2];
    const float* Wix = (const float*)d_in[3];
    const float* bix = (const float*)d_in[4];
    const float* Wih = (const float*)d_in[5];
    const float* bih = (const float*)d_in[6];
    const float* Wbx = (const float*)d_in[7];
    const float* bbx = (const float*)d_in[8];
    const float* Wbh = (const float*)d_in[9];
    const float* bbh = (const float*)d_in[10];

    float* out_h = (float*)d_out;
    float* out_c = out_h + (size_t)BATCH * HID;

    const size_t WT_BYTES = (size_t)NCAT * KCAT * 2;    // 16 MiB
    const size_t XC_BYTES = (size_t)BATCH * KCAT * 2;   // 16 MiB
    if (ws_size >= WT_BYTES + XC_BYTES) {
        unsigned short* Wt   = (unsigned short*)d_ws;
        unsigned short* Xcat = (unsigned short*)((char*)d_ws + WT_BYTES);
        pack_all<<<2048 + 1024, 256, 0, stream>>>(x, h, Wix, Wih, Wbx, Wbh, Xcat, Wt);
        lstm_fused<<<dim3(NCAT / BN, BATCH / BM), 512, 0, stream>>>(
            Xcat, Wt, c, bix, bih, bbx, bbh, out_h, out_c);
    } else {
        naive_lstm<<<dim3(HID / 256, BATCH), 256, 0, stream>>>(
            x, h, c, Wix, bix, Wih, bih, Wbx, bbx, Wbh, bbh, out_h, out_c);
    }
}

// Round 3
// 200.239 us; speedup vs baseline: 1.1384x; 1.0226x over previous
//
#include <hip/hip_runtime.h>
#include <hip/hip_bf16.h>
#include <stdint.h>
#include <stddef.h>

// GlobalLSTMCell — f32 in/out, bf16 MFMA compute.
//   ifo = sigmoid(x@W_ifo_x + b_ifo_x + h@W_ifo_h + b_ifo_h); i,f,o = split
//   a   = tanh(x@W_b_x + b_b_x + h@W_b_h + b_b_h)
//   c   = i*a + f*c_prev ; h = o*tanh(c) ; out = [h ; c] f32.
// R6: R5's XCD swizzle REVERTED (hurt 35%: FETCH fell but time rose -> GEMM
//     was never HBM-feed-bound). Real limiter: coarse 1-phase K-loop (2.4x
//     over pipe floors). Rebuilt as the verified 8-phase counted-vmcnt
//     template (T2+T3+T4+T5): K-half LDS sub-buffers [par][ks][256][4chunk],
//     1 half-tile staged/phase, 4-8 ds_read_b128 + 16 MFMA per phase between
//     paired raw barriers, vmcnt(4) at phases 4/8 only (tail drains 0).
//     Stage->read lead 5-6 phases; each half re-staged 1 phase after last read.

#define BATCH 4096
#define FEAT  1024
#define HID   1024
#define NCAT  4096
#define KCAT  2048

typedef __attribute__((ext_vector_type(8))) __bf16 bf16x8;
typedef __attribute__((ext_vector_type(4))) float  floatx4;

__device__ __forceinline__ unsigned short f2bf(float f) {
    __hip_bfloat16 b = __float2bfloat16(f);
    return *reinterpret_cast<unsigned short*>(&b);
}
__device__ __forceinline__ void gl2lds16(const unsigned short* g, unsigned short* l) {
    __builtin_amdgcn_global_load_lds(
        (const __attribute__((address_space(1))) void*)g,
        (__attribute__((address_space(3))) void*)l, 16, 0, 0);
}

// ---------------- fused pack: Wt first, then Xcat ----------------
// blocks [0,2048):      weight transpose tile (heavy -> dispatch first).
// blocks [2048,3072):   Xcat[m][k] = bf16([x | h_prev][m][k]), 4 rows/block.
//   Virtual W_cat[k][q]: k<1024 x-weights else h-weights; q<3072 -> W_ifo (g=q>>10,
//   j=q&1023) else W_b (g=3, j=q-3072). Dest Wt[np][k], np=(j>>4)*64+g*16+(j&15).
#define TP_PAD 72   // u16 row stride; 144 B = 9*16 -> uint4-aligned rows, odd word shift
__global__ __launch_bounds__(256)
void pack_all(const float* __restrict__ x, const float* __restrict__ h,
              const float* __restrict__ Wix, const float* __restrict__ Wih,
              const float* __restrict__ Wbx, const float* __restrict__ Wbh,
              unsigned short* __restrict__ Xcat, unsigned short* __restrict__ Wt) {
    __shared__ unsigned short tile[64 * TP_PAD];
    const int t = threadIdx.x;
    const int b = blockIdx.x;
    if (b >= 2048) {
        // ---- xh part: 4 rows per block, 8 elems per thread per row ----
        const int mbase = (b - 2048) * 4;
#pragma unroll
        for (int r = 0; r < 4; ++r) {
            const int m = mbase + r;
            const float* src = (t < 128) ? (x + (size_t)m * FEAT + t * 8)
                                         : (h + (size_t)m * HID + (t - 128) * 8);
            float4 v0 = *(const float4*)src;
            float4 v1 = *(const float4*)(src + 4);
            union { unsigned short s16[8]; uint4 v; } pk;
            pk.s16[0] = f2bf(v0.x); pk.s16[1] = f2bf(v0.y);
            pk.s16[2] = f2bf(v0.z); pk.s16[3] = f2bf(v0.w);
            pk.s16[4] = f2bf(v1.x); pk.s16[5] = f2bf(v1.y);
            pk.s16[6] = f2bf(v1.z); pk.s16[7] = f2bf(v1.w);
            *(uint4*)(Xcat + (size_t)m * KCAT + t * 8) = pk.v;
        }
        return;
    }
    // ---- wt part: 64x64 tile transpose ----
    const int tid = b;
    const int k0  = (tid & 31) * 64;
    const int q0  = (tid >> 5) * 64;
    const float* src; int stride, cb;
    if (q0 < 3072) { src = (k0 < FEAT) ? Wix : Wih; stride = 3072; cb = q0; }
    else           { src = (k0 < FEAT) ? Wbx : Wbh; stride = 1024; cb = q0 - 3072; }
    const int krow = (k0 < FEAT) ? k0 : (k0 - FEAT);
    {   // load 64x64 (k x q) coalesced on q, cvt bf16, vector LDS stores
        int kl = t >> 2;
        int c0 = (t & 3) * 16;
        const float* s = src + (size_t)(krow + kl) * stride + cb + c0;
        union { unsigned short s16[16]; uint4 v[2]; } tmp;
#pragma unroll
        for (int u = 0; u < 16; u += 4) {
            float4 v = *(const float4*)(s + u);
            tmp.s16[u + 0] = f2bf(v.x); tmp.s16[u + 1] = f2bf(v.y);
            tmp.s16[u + 2] = f2bf(v.z); tmp.s16[u + 3] = f2bf(v.w);
        }
        *(uint4*)&tile[kl * TP_PAD + c0]     = tmp.v[0];
        *(uint4*)&tile[kl * TP_PAD + c0 + 8] = tmp.v[1];
    }
    __syncthreads();
    {   // transpose out: thread = (q-col nl, k-chunk seg)
        int nl = t >> 2, seg = t & 3;
        int q = q0 + nl;
        int g, j;
        if (q < 3072) { g = q >> 10; j = q & 1023; }
        else          { g = 3;       j = q - 3072; }
        int np = ((j >> 4) << 6) + (g << 4) + (j & 15);
        union { unsigned short s16[16]; uint4 v[2]; } pk;
#pragma unroll
        for (int u = 0; u < 16; ++u)
            pk.s16[u] = tile[(seg * 16 + u) * TP_PAD + nl];
        uint4* dst = (uint4*)(Wt + (size_t)np * KCAT + k0 + seg * 16);
        dst[0] = pk.v[0];
        dst[1] = pk.v[1];
    }
}

// ---------------- fused GEMM + LSTM epilogue (256x256, BK=64, 8-phase) ----------------
#define BM 256
#define BN 256
#define BK 64
#define NIT 16         // 16 iterations x 2 K-tiles = KCAT/BK = 32
#define HALF 8192      // u16 per half-region: 256 rows x 4 chunks x 8 u16 (16 KB)

// LDS: A(par,ks) at (par*2+ks)*HALF ; B(par,ks) at 32768 + (par*2+ks)*HALF.
// par = K-tile parity (even tiles buf0, odd tiles buf1); ks = K-half (32 elems).
#define A_OFF(PAR, KS) (((PAR) * 2 + (KS)) * HALF)
#define B_OFF(PAR, KS) (32768 + ((PAR) * 2 + (KS)) * HALF)

// Stage one half-tile (256 rows x 32 k) = 2 gl2lds/thread. LDS dest linear in
// hslot (lane-consecutive 16B per instr); T2 swizzle applied on the GLOBAL
// source chunk (chofs ^ (row>>1)&3) so reads use the same XOR (both-sides).
__device__ __forceinline__ void stage_half(
    const unsigned short* __restrict__ src, int row0, int kt, int ks,
    unsigned short* __restrict__ ldsbase, int t) {
#pragma unroll
    for (int u = 0; u < 2; ++u) {
        int hslot = t + u * 512;               // 0..1023
        int row   = hslot >> 2;                // 0..255
        int chofs = hslot & 3;                 // 16B chunk within K-half
        int c     = chofs ^ ((row >> 1) & 3);  // swizzled source chunk
        gl2lds16(src + (size_t)(row0 + row) * KCAT + kt * BK + ks * 32 + c * 8,
                 ldsbase + hslot * 8);
    }
}

#define LOAD_BB(PAR, KS)                                                        \
    _Pragma("unroll")                                                           \
    for (int g = 0; g < 4; ++g)                                                 \
        bb[g] = *(const bf16x8*)&lds[B_OFF(PAR, KS) + (wn + g * 16 + lm) * 32 + cr];
#define LOAD_AA(PAR, KS, IQ)                                                    \
    _Pragma("unroll")                                                           \
    for (int ii = 0; ii < 4; ++ii)                                              \
        aa[ii] = *(const bf16x8*)&lds[A_OFF(PAR, KS) + (wm + (IQ) * 64 + ii * 16 + lm) * 32 + cr];
#define DO_MFMA(IQ)                                                             \
    asm volatile("s_waitcnt lgkmcnt(0)" ::: "memory");                          \
    __builtin_amdgcn_s_setprio(1);                                              \
    _Pragma("unroll")                                                           \
    for (int ii = 0; ii < 4; ++ii)                                              \
        _Pragma("unroll")                                                       \
        for (int g = 0; g < 4; ++g)                                             \
            acc[(IQ) * 4 + ii][g] = __builtin_amdgcn_mfma_f32_16x16x32_bf16(    \
                aa[ii], bb[g], acc[(IQ) * 4 + ii][g], 0, 0, 0);                 \
    __builtin_amdgcn_s_setprio(0);
#define BAR __builtin_amdgcn_s_barrier();

__global__ __launch_bounds__(512, 2)
void lstm_fused(const unsigned short* __restrict__ Xcat,
                const unsigned short* __restrict__ Wt,
                const float* __restrict__ c_prev,
                const float* __restrict__ bix, const float* __restrict__ bih,
                const float* __restrict__ bbx, const float* __restrict__ bbh,
                float* __restrict__ out_h, float* __restrict__ out_c) {
    __shared__ unsigned short lds[65536];       // 128 KiB
    const int t    = threadIdx.x;
    const int lane = t & 63;
    const int wid  = t >> 6;                    // 0..7
    const int wm   = (wid >> 2) * 128;          // M-half of block tile
    const int wn   = (wid & 3) * 64;            // N-quarter (one gate-group)
    const int m0   = blockIdx.y * BM;
    const int n0   = blockIdx.x * BN;
    const int lm   = lane & 15;
    const int lk   = lane >> 4;                 // chunk-within-half (c&3)
    const int cr   = (lk ^ ((lm >> 1) & 3)) * 8;  // swizzled read chunk (u16)

    floatx4 acc[8][4];
#pragma unroll
    for (int i = 0; i < 8; ++i)
#pragma unroll
        for (int g = 0; g < 4; ++g) acc[i][g] = (floatx4){0.f, 0.f, 0.f, 0.f};

    // ---- prologue: K0 (both halves) + K1-ks0 = 6 half-tiles, 12 loads ----
    stage_half(Xcat, m0, 0, 0, lds + A_OFF(0, 0), t);
    stage_half(Wt,   n0, 0, 0, lds + B_OFF(0, 0), t);
    stage_half(Xcat, m0, 0, 1, lds + A_OFF(0, 1), t);
    stage_half(Wt,   n0, 0, 1, lds + B_OFF(0, 1), t);
    stage_half(Xcat, m0, 1, 0, lds + A_OFF(1, 0), t);
    stage_half(Wt,   n0, 1, 0, lds + B_OFF(1, 0), t);
    asm volatile("s_waitcnt vmcnt(4)" ::: "memory");  // K0 landed; K1-ks0 in flight
    BAR

    bf16x8 aa[4], bb[4];

    for (int it = 0; it < NIT; ++it) {
        const int k1 = 2 * it + 1, k2 = 2 * it + 2, k3 = 2 * it + 3;
        const bool more = (it < NIT - 1);

        // P1: compute(even,ks0,iq0,+bb) | stage A(odd,ks1)<-k1
        LOAD_BB(0, 0) LOAD_AA(0, 0, 0)
        stage_half(Xcat, m0, k1, 1, lds + A_OFF(1, 1), t);
        BAR DO_MFMA(0) BAR
        // P2: compute(even,ks0,iq1) | stage B(odd,ks1)<-k1
        LOAD_AA(0, 0, 1)
        stage_half(Wt, n0, k1, 1, lds + B_OFF(1, 1), t);
        BAR DO_MFMA(1) BAR
        // P3: compute(even,ks1,iq0,+bb) | stage A(even,ks0)<-k2
        LOAD_BB(0, 1) LOAD_AA(0, 1, 0)
        if (more) stage_half(Xcat, m0, k2, 0, lds + A_OFF(0, 0), t);
        BAR DO_MFMA(0) BAR
        // P4: compute(even,ks1,iq1) | stage B(even,ks0)<-k2 | SYNC
        LOAD_AA(0, 1, 1)
        if (more) {
            stage_half(Wt, n0, k2, 0, lds + B_OFF(0, 0), t);
            asm volatile("s_waitcnt vmcnt(4)" ::: "memory");
        } else {
            asm volatile("s_waitcnt vmcnt(0)" ::: "memory");
        }
        BAR DO_MFMA(1) BAR
        // P5: compute(odd,ks0,iq0,+bb) | stage A(even,ks1)<-k2
        LOAD_BB(1, 0) LOAD_AA(1, 0, 0)
        if (more) stage_half(Xcat, m0, k2, 1, lds + A_OFF(0, 1), t);
        BAR DO_MFMA(0) BAR
        // P6: compute(odd,ks0,iq1) | stage B(even,ks1)<-k2
        LOAD_AA(1, 0, 1)
        if (more) stage_half(Wt, n0, k2, 1, lds + B_OFF(0, 1), t);
        BAR DO_MFMA(1) BAR
        // P7: compute(odd,ks1,iq0,+bb) | stage A(odd,ks0)<-k3
        LOAD_BB(1, 1) LOAD_AA(1, 1, 0)
        if (more) stage_half(Xcat, m0, k3, 0, lds + A_OFF(1, 0), t);
        BAR DO_MFMA(0) BAR
        // P8: compute(odd,ks1,iq1) | stage B(odd,ks0)<-k3 | SYNC
        LOAD_AA(1, 1, 1)
        if (more) {
            stage_half(Wt, n0, k3, 0, lds + B_OFF(1, 0), t);
            asm volatile("s_waitcnt vmcnt(4)" ::: "memory");
        }
        BAR DO_MFMA(1) BAR
    }

    // ---- LSTM epilogue ----
    // acc[idx][g][r]: m = m0 + wm + idx*16 + (lane>>4)*4 + r,
    //                 gate g at j = ((n0+wn)>>6)*16 + lm.
    const int j  = (((n0 + wn) >> 6) << 4) + lm;
    const float bi = bix[j]           + bih[j];
    const float bf = bix[HID + j]     + bih[HID + j];
    const float bo = bix[2 * HID + j] + bih[2 * HID + j];
    const float ba = bbx[j]           + bbh[j];
#pragma unroll
    for (int i = 0; i < 8; ++i) {
#pragma unroll
        for (int r = 0; r < 4; ++r) {
            int m = m0 + wm + i * 16 + (lk * 4) + r;
            float pi = acc[i][0][r] + bi;
            float pf = acc[i][1][r] + bf;
            float po = acc[i][2][r] + bo;
            float pa = acc[i][3][r] + ba;
            float ig = 1.f / (1.f + __expf(-pi));
            float fg = 1.f / (1.f + __expf(-pf));
            float og = 1.f / (1.f + __expf(-po));
            float av = 2.f / (1.f + __expf(-2.f * pa)) - 1.f;
            float cp = c_prev[(size_t)m * HID + j];
            float cv = ig * av + fg * cp;
            float hv = og * (2.f / (1.f + __expf(-2.f * cv)) - 1.f);
            out_h[(size_t)m * HID + j] = hv;
            out_c[(size_t)m * HID + j] = cv;
        }
    }
}

// ---------------- naive fallback (ws too small) ----------------
__global__ void naive_lstm(const float* __restrict__ x, const float* __restrict__ h,
                           const float* __restrict__ cvp,
                           const float* __restrict__ Wix, const float* __restrict__ bix,
                           const float* __restrict__ Wih, const float* __restrict__ bih,
                           const float* __restrict__ Wbx, const float* __restrict__ bbx,
                           const float* __restrict__ Wbh, const float* __restrict__ bbh,
                           float* __restrict__ out_h, float* __restrict__ out_c) {
    const int j = blockIdx.x * 256 + threadIdx.x;
    const int m = blockIdx.y;
    float ai = 0.f, af = 0.f, ao = 0.f, aa = 0.f;
    for (int k = 0; k < FEAT; ++k) {
        float xk = x[(size_t)m * FEAT + k];
        ai += xk * Wix[(size_t)k * 3072 + j];
        af += xk * Wix[(size_t)k * 3072 + HID + j];
        ao += xk * Wix[(size_t)k * 3072 + 2 * HID + j];
        aa += xk * Wbx[(size_t)k * HID + j];
    }
    for (int k = 0; k < HID; ++k) {
        float hk = h[(size_t)m * HID + k];
        ai += hk * Wih[(size_t)k * 3072 + j];
        af += hk * Wih[(size_t)k * 3072 + HID + j];
        ao += hk * Wih[(size_t)k * 3072 + 2 * HID + j];
        aa += hk * Wbh[(size_t)k * HID + j];
    }
    ai += bix[j] + bih[j];
    af += bix[HID + j] + bih[HID + j];
    ao += bix[2 * HID + j] + bih[2 * HID + j];
    aa += bbx[j] + bbh[j];
    float ig = 1.f / (1.f + __expf(-ai));
    float fg = 1.f / (1.f + __expf(-af));
    float og = 1.f / (1.f + __expf(-ao));
    float av = 2.f / (1.f + __expf(-2.f * aa)) - 1.f;
    float cp = cvp[(size_t)m * HID + j];
    float cc = ig * av + fg * cp;
    float hh = og * (2.f / (1.f + __expf(-2.f * cc)) - 1.f);
    out_h[(size_t)m * HID + j] = hh;
    out_c[(size_t)m * HID + j] = cc;
}

extern "C" void kernel_launch(void* const* d_in, const int* in_sizes, int n_in,
                              void* d_out, int out_size, void* d_ws, size_t ws_size,
                              hipStream_t stream) {
    const float* x   = (const float*)d_in[0];
    const float* h   = (const float*)d_in[1];
    const float* c   = (const float*)d_in[2];
    const float* Wix = (const float*)d_in[3];
    const float* bix = (const float*)d_in[4];
    const float* Wih = (const float*)d_in[5];
    const float* bih = (const float*)d_in[6];
    const float* Wbx = (const float*)d_in[7];
    const float* bbx = (const float*)d_in[8];
    const float* Wbh = (const float*)d_in[9];
    const float* bbh = (const float*)d_in[10];

    float* out_h = (float*)d_out;
    float* out_c = out_h + (size_t)BATCH * HID;

    const size_t WT_BYTES = (size_t)NCAT * KCAT * 2;    // 16 MiB
    const size_t XC_BYTES = (size_t)BATCH * KCAT * 2;   // 16 MiB
    if (ws_size >= WT_BYTES + XC_BYTES) {
        unsigned short* Wt   = (unsigned short*)d_ws;
        unsigned short* Xcat = (unsigned short*)((char*)d_ws + WT_BYTES);
        pack_all<<<2048 + 1024, 256, 0, stream>>>(x, h, Wix, Wih, Wbx, Wbh, Xcat, Wt);
        lstm_fused<<<dim3(NCAT / BN, BATCH / BM), 512, 0, stream>>>(
            Xcat, Wt, c, bix, bih, bbx, bbh, out_h, out_c);
    } else {
        naive_lstm<<<dim3(HID / 256, BATCH), 256, 0, stream>>>(
            x, h, c, Wix, bix, Wih, bih, Wbx, bbx, Wbh, bbh, out_h, out_c);
    }
}